// Round 1
// baseline (5169.195 us; speedup 1.0000x reference)
//
#include <hip/hip_runtime.h>

typedef __attribute__((ext_vector_type(8))) short short8;
typedef __attribute__((ext_vector_type(4))) float floatx4;

#define B_SZ 256
#define T_SZ 256
#define DIN  512
#define H_SZ 1024
#define G4   4096
#define KTOT 1536
#define NKS  24   // 1536 / 64

__device__ __forceinline__ unsigned short f2bf(float f){
  unsigned int u = __float_as_uint(f);
  u += 0x7fffu + ((u >> 16) & 1u);
  return (unsigned short)(u >> 16);
}
__device__ __forceinline__ unsigned int pack2(float a, float b){
  return (unsigned int)f2bf(a) | ((unsigned int)f2bf(b) << 16);
}

// ---------------- prep kernels ----------------
__global__ void prep_wcat(const float* __restrict__ wx, const float* __restrict__ wh,
                          const float* __restrict__ bx, const float* __restrict__ bh,
                          unsigned short* __restrict__ Wcat, float* __restrict__ bias){
  int gid = blockIdx.x * blockDim.x + threadIdx.x;
  int idx = gid * 8;
  int g = idx / KTOT;
  int k = idx - g * KTOT;
  const float* src = (k < DIN) ? (wx + (size_t)g * DIN + k)
                               : (wh + (size_t)g * H_SZ + (k - DIN));
  float4 f0 = *(const float4*)(src);
  float4 f1 = *(const float4*)(src + 4);
  uint4 v = make_uint4(pack2(f0.x,f0.y), pack2(f0.z,f0.w), pack2(f1.x,f1.y), pack2(f1.z,f1.w));
  *(uint4*)(Wcat + (size_t)g * KTOT + k) = v;
  if (gid < G4) bias[gid] = bx[gid] + bh[gid];
}

__global__ void prep_wfc(const float* __restrict__ wfc, unsigned short* __restrict__ Wfcb){
  int gid = blockIdx.x * blockDim.x + threadIdx.x;
  int idx = gid * 8;
  int n = idx >> 10;
  int k = idx & 1023;
  uint4 v;
  if (n < 1000){
    const float* src = wfc + (size_t)n * 1024 + k;
    float4 f0 = *(const float4*)(src);
    float4 f1 = *(const float4*)(src + 4);
    v = make_uint4(pack2(f0.x,f0.y), pack2(f0.z,f0.w), pack2(f1.x,f1.y), pack2(f1.z,f1.w));
  } else {
    v = make_uint4(0u, 0u, 0u, 0u);
  }
  *(uint4*)(Wfcb + idx) = v;
}

__global__ void init_state(float* __restrict__ c, unsigned short* __restrict__ h0,
                           unsigned short* __restrict__ h1){
  int gid = blockIdx.x * blockDim.x + threadIdx.x;
  c[gid] = 0.0f;
  h0[gid] = 0;
  h1[gid] = 0;
}

// ---------------- fused LSTM step ----------------
// grid = 256 wgs: bx>>2 = hidden-block (16 units), bx&3 = batch-block (64 rows)
// per wg: gates[64 rows][64 cols] where col = gate*16 + hid  (gates i,f,g,o)
__global__ __launch_bounds__(256, 1)
void lstm_step(const float* __restrict__ x, const unsigned short* __restrict__ Wcat,
               const float* __restrict__ bias, const unsigned short* __restrict__ h_in,
               unsigned short* __restrict__ h_out, float* __restrict__ c, int t){
  __shared__ __align__(16) char smA[2][64 * 128];
  __shared__ __align__(16) char smB[2][64 * 128];
  __shared__ float Gt[64 * 68];
  __shared__ float Bls[64];

  const int tid  = threadIdx.x;
  const int bx   = blockIdx.x;
  const int hb0  = (bx >> 2) * 16;
  const int b0   = (bx & 3) * 64;
  const int lane = tid & 63;
  const int wave = tid >> 6;
  const int wrow = (wave >> 1) * 32;
  const int wcol = (wave & 1) * 32;

  const int sr  = tid >> 2;          // staging row 0..63
  const int skc = (tid & 3) * 16;    // element col offset within 64-wide K tile

  if (tid < 64) Bls[tid] = bias[(size_t)(tid >> 4) * H_SZ + hb0 + (tid & 15)];

  auto stage = [&](int ks, int p){
    // ---- A tile: rows = batch, cols = K (x part then h part), bf16, swizzled
    {
      int kg = ks * 64 + skc;
      uint4 v0, v1;
      if (kg < DIN){
        const float* src = x + ((size_t)(b0 + sr) * T_SZ + t) * DIN + kg;
        float4 f0 = *(const float4*)(src);
        float4 f1 = *(const float4*)(src + 4);
        float4 f2 = *(const float4*)(src + 8);
        float4 f3 = *(const float4*)(src + 12);
        v0 = make_uint4(pack2(f0.x,f0.y), pack2(f0.z,f0.w), pack2(f1.x,f1.y), pack2(f1.z,f1.w));
        v1 = make_uint4(pack2(f2.x,f2.y), pack2(f2.z,f2.w), pack2(f3.x,f3.y), pack2(f3.z,f3.w));
      } else {
        const unsigned short* src = h_in + (size_t)(b0 + sr) * H_SZ + (kg - DIN);
        v0 = *(const uint4*)(src);
        v1 = *(const uint4*)(src + 8);
      }
      char* base = smA[p] + sr * 128;
      int xr = (sr & 7) << 4;
      int s0 = skc * 2;
      *(uint4*)(base + ( s0        ^ xr)) = v0;
      *(uint4*)(base + ((s0 + 16)  ^ xr)) = v1;
    }
    // ---- B tile: rows = gate cols (gate*16+hid -> W row gate*1024+hb0+hid)
    {
      int gate = sr >> 4, hid = sr & 15;
      const unsigned short* src = Wcat + (size_t)(gate * H_SZ + hb0 + hid) * KTOT + ks * 64 + skc;
      uint4 v0 = *(const uint4*)(src);
      uint4 v1 = *(const uint4*)(src + 8);
      char* base = smB[p] + sr * 128;
      int xr = (sr & 7) << 4;
      int s0 = skc * 2;
      *(uint4*)(base + ( s0        ^ xr)) = v0;
      *(uint4*)(base + ((s0 + 16)  ^ xr)) = v1;
    }
  };

  auto rdfrag = [&](const char* sm, int row, int ke) -> short8 {
    int byte = row * 128 + (((ke * 2) ^ ((row & 7) << 4)));
    return *(const short8*)(sm + byte);
  };

  floatx4 acc00 = {0.f,0.f,0.f,0.f}, acc01 = {0.f,0.f,0.f,0.f};
  floatx4 acc10 = {0.f,0.f,0.f,0.f}, acc11 = {0.f,0.f,0.f,0.f};

  stage(0, 0);
  __syncthreads();
  for (int ks = 0; ks < NKS; ++ks){
    int p = ks & 1;
    if (ks + 1 < NKS) stage(ks + 1, p ^ 1);
    const char* A  = smA[p];
    const char* Bm = smB[p];
    #pragma unroll
    for (int kk = 0; kk < 2; ++kk){
      int ke = kk * 32 + (lane >> 4) * 8;
      short8 a0 = rdfrag(A,  wrow +      (lane & 15), ke);
      short8 a1 = rdfrag(A,  wrow + 16 + (lane & 15), ke);
      short8 b0 = rdfrag(Bm, wcol +      (lane & 15), ke);
      short8 b1 = rdfrag(Bm, wcol + 16 + (lane & 15), ke);
      acc00 = __builtin_amdgcn_mfma_f32_16x16x32_bf16(a0, b0, acc00, 0, 0, 0);
      acc01 = __builtin_amdgcn_mfma_f32_16x16x32_bf16(a0, b1, acc01, 0, 0, 0);
      acc10 = __builtin_amdgcn_mfma_f32_16x16x32_bf16(a1, b0, acc10, 0, 0, 0);
      acc11 = __builtin_amdgcn_mfma_f32_16x16x32_bf16(a1, b1, acc11, 0, 0, 0);
    }
    __syncthreads();
  }

  // gates -> LDS (padded stride 68 to dodge bank conflicts)
  {
    int drow = (lane >> 4) * 4;
    int dcol = lane & 15;
    #pragma unroll
    for (int r = 0; r < 4; ++r){
      Gt[(wrow +      drow + r) * 68 + wcol +      dcol] = acc00[r];
      Gt[(wrow +      drow + r) * 68 + wcol + 16 + dcol] = acc01[r];
      Gt[(wrow + 16 + drow + r) * 68 + wcol +      dcol] = acc10[r];
      Gt[(wrow + 16 + drow + r) * 68 + wcol + 16 + dcol] = acc11[r];
    }
  }
  __syncthreads();

  // elementwise: i,f,g,o -> c,h
  #pragma unroll
  for (int j = 0; j < 4; ++j){
    int pp  = tid + j * 256;       // 0..1023 = 64 rows x 16 hid
    int row = pp >> 4, hid = pp & 15;
    float gi = Gt[row * 68 +      hid] + Bls[     hid];
    float gf = Gt[row * 68 + 16 + hid] + Bls[16 + hid];
    float gg = Gt[row * 68 + 32 + hid] + Bls[32 + hid];
    float go = Gt[row * 68 + 48 + hid] + Bls[48 + hid];
    float iv = 1.0f / (1.0f + __expf(-gi));
    float fv = 1.0f / (1.0f + __expf(-gf));
    float e2 = __expf(-2.0f * fmaxf(fminf(gg, 30.0f), -30.0f));
    float gv = (1.0f - e2) / (1.0f + e2);
    float ov = 1.0f / (1.0f + __expf(-go));
    size_t ci = (size_t)(b0 + row) * H_SZ + hb0 + hid;
    float cn = c[ci] * fv + iv * gv;
    c[ci] = cn;
    float e2c = __expf(-2.0f * fmaxf(fminf(cn, 30.0f), -30.0f));
    float th  = (1.0f - e2c) / (1.0f + e2c);
    h_out[ci] = f2bf(ov * th);
  }
}

// ---------------- final FC: out[256][1000] = h @ Wfc^T + b ----------------
__global__ __launch_bounds__(256, 1)
void fc_kernel(const unsigned short* __restrict__ h, const unsigned short* __restrict__ wfc,
               const float* __restrict__ bfc, float* __restrict__ out){
  int bx = blockIdx.x, tid = threadIdx.x;
  int wave = tid >> 6, lane = tid & 63;
  int row0 = (bx >> 4) * 64 + wave * 16;
  int col0 = (bx & 15) * 64;
  int lr = lane & 15, lk = (lane >> 4) * 8;
  floatx4 acc[4] = {{0.f,0.f,0.f,0.f},{0.f,0.f,0.f,0.f},{0.f,0.f,0.f,0.f},{0.f,0.f,0.f,0.f}};
  #pragma unroll 4
  for (int ks = 0; ks < 32; ++ks){
    int k = ks * 32 + lk;
    short8 a = *(const short8*)(h + (size_t)(row0 + lr) * 1024 + k);
    #pragma unroll
    for (int fj = 0; fj < 4; ++fj){
      short8 b = *(const short8*)(wfc + (size_t)(col0 + fj * 16 + lr) * 1024 + k);
      acc[fj] = __builtin_amdgcn_mfma_f32_16x16x32_bf16(a, b, acc[fj], 0, 0, 0);
    }
  }
  #pragma unroll
  for (int fj = 0; fj < 4; ++fj){
    int col = col0 + fj * 16 + lr;
    if (col < 1000){
      #pragma unroll
      for (int r = 0; r < 4; ++r){
        int row = row0 + (lane >> 4) * 4 + r;
        out[(size_t)row * 1000 + col] = acc[fj][r] + bfc[col];
      }
    }
  }
}

// ---------------- launch ----------------
extern "C" void kernel_launch(void* const* d_in, const int* in_sizes, int n_in,
                              void* d_out, int out_size, void* d_ws, size_t ws_size,
                              hipStream_t stream){
  const float* x    = (const float*)d_in[0];
  const float* wx2h = (const float*)d_in[1];
  const float* bx2h = (const float*)d_in[2];
  const float* wh2h = (const float*)d_in[3];
  const float* bh2h = (const float*)d_in[4];
  const float* wfc  = (const float*)d_in[5];
  const float* bfc  = (const float*)d_in[6];
  float* out = (float*)d_out;
  char* ws = (char*)d_ws;

  // ws layout (bytes)
  unsigned short* Wcat = (unsigned short*)(ws + 0);            // 4096*1536*2 = 12,582,912
  unsigned short* Wfcb = (unsigned short*)(ws + 12582912);     // 1024*1024*2 =  2,097,152
  float*          bias = (float*)         (ws + 14680064);     // 4096*4      =     16,384
  unsigned short* h0   = (unsigned short*)(ws + 14696448);     // 256*1024*2  =    524,288
  unsigned short* h1   = (unsigned short*)(ws + 15220736);     // 256*1024*2  =    524,288
  float*          c    = (float*)         (ws + 15745024);     // 256*1024*4  =  1,048,576
  // total ~16.8 MB

  hipLaunchKernelGGL(prep_wcat, dim3(3072), dim3(256), 0, stream, wx2h, wh2h, bx2h, bh2h, Wcat, bias);
  hipLaunchKernelGGL(prep_wfc,  dim3(512),  dim3(256), 0, stream, wfc, Wfcb);
  hipLaunchKernelGGL(init_state,dim3(1024), dim3(256), 0, stream, c, h0, h1);

  for (int t = 0; t < 256; ++t){
    unsigned short* hin  = (t & 1) ? h1 : h0;
    unsigned short* hout = (t & 1) ? h0 : h1;
    hipLaunchKernelGGL(lstm_step, dim3(256), dim3(256), 0, stream, x, Wcat, bias, hin, hout, c, t);
  }
  // after 256 steps (even), final h is in h0
  hipLaunchKernelGGL(fc_kernel, dim3(64), dim3(256), 0, stream, h0, Wfcb, bfc, out);
}